// Round 6
// baseline (419.782 us; speedup 1.0000x reference)
//
#include <hip/hip_runtime.h>
#include <hip/hip_bf16.h>

// ARNOLD_ENC: spike-latency encoding.
//   bin(b,n) = int(2.5*|trace[b,f]-center[c]| / 0.1 + 1); spike at t=bin iff times<=10 and bin<100.
//   out: int32[100][1024][1024] = 400 MiB. Store-BW bound; 66 us floor at the fill's 6.33 TB/s.
//
// Measurement: ~331 us/iter is harness poison (1.6 GiB d_ws fill 265 us + d_out fill ~66 us).
// R1 95us -> R2 contiguous 92us -> R4 nontemporal 89us -> R5 LDS-staged pure-store loop 85us
//   (~5.2 TB/s, 82% of the harness fill's own rate).
// R6: fuse bins into the stream kernel. A block's window = 8 b-rows x all n, so each thread
//   computes its 32 bins (8 rows x 4 centers, IEEE f32 div) ONCE into 8 packed registers and
//   reuses them across 10 planes x 8 stores. Removes: 2nd launch, serialization bubble,
//   bins 1MB write + 10MB re-read. Pure-store inner loop, no LDS, no syncthreads.

#define BB 1024
#define FF 128
#define TT 100
#define GROUPS_PER_PLANE (BB * 256)   // 262144 int4 groups/plane; group p = b*256 + nq
#define ROWS_PER_BLOCK 8              // b-rows per block (window = 8*256 groups = 32 KB/plane)
#define WINS (BB / ROWS_PER_BLOCK)    // 128
#define PCH 10                        // planes per block
#define PCHUNKS (TT / PCH)            // 10

typedef int iv4 __attribute__((ext_vector_type(4)));   // native vector for nontemporal builtin

__global__ __launch_bounds__(256) void arnold_fused_kernel(
        const float* __restrict__ trace,
        const float* __restrict__ center,
        iv4* __restrict__ out) {
    const int w   = blockIdx.x;       // 0..127  window (8 consecutive b-rows)
    const int pc  = blockIdx.y;       // 0..9    plane chunk
    const int tid = threadIdx.x;      // 0..255  = nq (n-quad index within row)

    const int f  = tid >> 1;          // feature for this n-quad
    const int c0 = (tid & 1) << 2;    // center offset: 0 or 4

    float cen[4];
#pragma unroll
    for (int j = 0; j < 4; ++j) cen[j] = center[c0 + j];   // L2-resident broadcast

    // Compute this thread's 32 bins once (8 b-rows x 4 centers). IEEE f32 (no fast-math):
    // correctly-rounded div matches np/jnp binning bit-exactly. Values >=100 never match t.
    uchar4 binv[ROWS_PER_BLOCK];
#pragma unroll
    for (int i = 0; i < ROWS_PER_BLOCK; ++i) {
        const int b = w * ROWS_PER_BLOCK + i;
        const float x = trace[b * FF + f];      // block reads 8 rows x 512 B, coalesced, L2-hot
        unsigned char v[4];
#pragma unroll
        for (int j = 0; j < 4; ++j) {
            float tms = 2.5f * fabsf(x - cen[j]);
            unsigned bb = (tms > 10.0f) ? 255u : (unsigned)(tms / 0.1f + 1.0f);  // 1..101 | 255
            v[j] = (unsigned char)bb;
        }
        binv[i] = make_uchar4(v[0], v[1], v[2], v[3]);
    }

    // Pure-store loop: 10 planes x 8 stores/thread, 16 B/lane, 32 KB contiguous per plane.
    const int t0 = pc * PCH;
    iv4* base = out + (size_t)w * (ROWS_PER_BLOCK * 256) + tid;
    for (int tt = 0; tt < PCH; ++tt) {
        const int t = t0 + tt;
        iv4* op = base + (size_t)t * GROUPS_PER_PLANE;
#pragma unroll
        for (int i = 0; i < ROWS_PER_BLOCK; ++i) {
            const uchar4 c = binv[i];
            iv4 v;
            v.x = (c.x == t) ? 1 : 0;
            v.y = (c.y == t) ? 1 : 0;
            v.z = (c.z == t) ? 1 : 0;
            v.w = (c.w == t) ? 1 : 0;
            __builtin_nontemporal_store(v, op + i * 256);
        }
    }
}

extern "C" void kernel_launch(void* const* d_in, const int* in_sizes, int n_in,
                              void* d_out, int out_size, void* d_ws, size_t ws_size,
                              hipStream_t stream) {
    const float* trace  = (const float*)d_in[0];   // [1024,128] f32
    const float* center = (const float*)d_in[1];   // [8] f32
    iv4* out = (iv4*)d_out;                        // [100][1024][1024] int32

    dim3 grid(WINS, PCHUNKS);                      // (128, 10) = 1280 blocks, 5/CU
    arnold_fused_kernel<<<grid, 256, 0, stream>>>(trace, center, out);
}